// Round 11
// baseline (208.109 us; speedup 1.0000x reference)
//
#include <hip/hip_runtime.h>
#include <hip/hip_bf16.h>
#include <stdint.h>

typedef __bf16 bf16;
typedef __bf16 bf16x8 __attribute__((ext_vector_type(8)));
typedef float f32x16 __attribute__((ext_vector_type(16)));

#define TAU (1.0f/30.0f)

#define NB 32
#define CI 256
#define CO 256
#define HH 64
#define WW 64
#define HID 64

// wn fragment-linear (32x32x16): [n][c(8)][kk(9)][cot(4)][sub(2)][cbg(2)][lane(64)][j(8)]
//   el = agg_m Wbank[co=cot*64+cbg*32+(l&31)][m][ci=c*32+sub*16+(l>>5)*8+j][kk]
#define WN_ELEMS ((size_t)NB*589824)
#define WN_BYTES (WN_ELEMS*2)
// xb padded layout: [n][cg(32)][hr(66)][wl(66)][j(8)] bf16, margins zeroed
#define PLANE_E 34848          // 66*66*8
#define XB_ELEMS ((size_t)NB*32*PLANE_E)
#define XB_BYTES (XB_ELEMS*2)  // 71.37 MB

__device__ __forceinline__ void async16(void* lds_uniform_base, const void* g_perlane) {
  __builtin_amdgcn_global_load_lds(
      (const __attribute__((address_space(1))) uint32_t*)g_perlane,
      (__attribute__((address_space(3))) uint32_t*)lds_uniform_base, 16, 0, 0);
}

// Fused fp32->bf16 repack (padded layout) + global average pool.
__global__ void cvt_pool_kernel(const float* __restrict__ x, bf16* __restrict__ xb,
                                float* __restrict__ pooled) {
  const int cg = blockIdx.x, n = blockIdx.y, tid = threadIdx.x;
  const float* base = x + ((size_t)n*CI + cg*8)*4096;
  bf16* ob = xb + ((size_t)n*32 + cg)*PLANE_E;
  for (int i = tid; i < 260; i += 256) {
    int hr, wl;
    if (i < 66)       { hr = 0;       wl = i; }
    else if (i < 132) { hr = 65;      wl = i - 66; }
    else if (i < 196) { hr = i - 131; wl = 0; }
    else              { hr = i - 195; wl = 65; }
    *(int4*)(ob + ((size_t)hr*66 + wl)*8) = int4{0,0,0,0};
  }
  float s[8];
#pragma unroll
  for (int j = 0; j < 8; ++j) s[j] = 0.f;
  for (int it = 0; it < 16; ++it) {
    int pos = it*256 + tid;
    int h = pos >> 6, w = pos & 63;
    bf16x8 o;
#pragma unroll
    for (int j = 0; j < 8; ++j) {
      float v = base[(size_t)j*4096 + pos];
      s[j] += v;
      o[j] = (bf16)v;
    }
    *(bf16x8*)(ob + ((size_t)(h+1)*66 + (w+1))*8) = o;
  }
  __shared__ float red[4][8];
#pragma unroll
  for (int j = 0; j < 8; ++j)
#pragma unroll
    for (int off = 32; off; off >>= 1) s[j] += __shfl_xor(s[j], off);
  int wv = tid >> 6, lane = tid & 63;
  if (lane == 0)
#pragma unroll
    for (int j = 0; j < 8; ++j) red[wv][j] = s[j];
  __syncthreads();
  if (tid < 8) {
    float t = red[0][tid] + red[1][tid] + red[2][tid] + red[3][tid];
    pooled[n*CI + cg*8 + tid] = t * (1.0f/4096.0f);
  }
}

__global__ void attn_kernel(const float* __restrict__ pooled,
                            const float* __restrict__ w1, const float* __restrict__ b1,
                            const float* __restrict__ w2, const float* __restrict__ b2,
                            float* __restrict__ pi) {
  int n = blockIdx.x, h = threadIdx.x;        // 64 threads
  __shared__ float hm[HID];
  __shared__ float lgs[4];
  const float* pr = pooled + n*CI;
  float s = b1[h];
  for (int c = 0; c < CI; ++c) s += pr[c] * w1[h*CI + c];
  hm[h] = s > 0.f ? s : 0.f;
  __syncthreads();
  if (h < 4) {
    float lg = b2[h];
    for (int k = 0; k < HID; ++k) lg += hm[k] * w2[h*HID + k];
    lgs[h] = lg * TAU;
  }
  __syncthreads();
  if (h == 0) {
    float mx = fmaxf(fmaxf(lgs[0], lgs[1]), fmaxf(lgs[2], lgs[3]));
    float e0 = expf(lgs[0]-mx), e1 = expf(lgs[1]-mx), e2 = expf(lgs[2]-mx), e3 = expf(lgs[3]-mx);
    float inv = 1.f / (e0+e1+e2+e3);
    pi[n*4+0] = e0*inv; pi[n*4+1] = e1*inv; pi[n*4+2] = e2*inv; pi[n*4+3] = e3*inv;
  }
}

// agg for 32x32x16 fragment layout. 1152 waves, one per (c,kk,cot,sub,cbg).
__global__ void agg_kernel(const float* __restrict__ Wbank, const float* __restrict__ pi,
                           bf16* __restrict__ wn) {
  int wid = blockIdx.x * 4 + (threadIdx.x >> 6);   // 0..1151
  int lane = threadIdx.x & 63;
  int c = wid / 144;
  int rem = wid - c*144;
  int kk  = rem >> 4;
  int r2  = rem & 15;
  int cot = r2 >> 2;
  int sub = (r2 >> 1) & 1;
  int cbg = r2 & 1;
  int co  = cot*64 + cbg*32 + (lane & 31);
  int ci0 = c*32 + sub*16 + (lane >> 5)*8;
  float w[4][8];
#pragma unroll
  for (int m = 0; m < 4; ++m)
#pragma unroll
    for (int j = 0; j < 8; ++j)
      w[m][j] = Wbank[(size_t)((co*4 + m)*256 + ci0 + j)*9 + kk];
  bf16* ob = wn + (size_t)c*73728 + (size_t)kk*8192 + cot*2048 + sub*1024 + cbg*512 + lane*8;
  for (int n = 0; n < NB; ++n) {
    float p0 = pi[n*4+0], p1 = pi[n*4+1], p2 = pi[n*4+2], p3 = pi[n*4+3];
    bf16x8 o;
#pragma unroll
    for (int j = 0; j < 8; ++j)
      o[j] = (bf16)(p0*w[0][j] + p1*w[1][j] + p2*w[2][j] + p3*w[3][j]);
    *(bf16x8*)(ob + (size_t)n*589824) = o;
  }
}

// Conv R11: block = 8 rows x 64 co; 4 waves, wave wv owns rows h0+wv*2, h0+wv*2+1.
// MFMA 32x32x16: wave tile = 2 co-frags x 2 w-frags x 2 rows; 144 MFMA/wave-chunk.
// A: LDS double-buffered (36 frags/chunk), staged one chunk ahead.
// B: global->VGPR, 4 row-slots x (sub,f), R8 distance-2 schedule + cross-chunk prefetch.
#define WA_E (36*512)        // 18432 el = 36864 B per buffer

// B-load: slot P[4] <- row r (padded h0+wv*2+r), chunk cc; P[sub*2+f]
#define LDB(P, r, cc) { _Pragma("unroll") \
  for (int sf = 0; sf < 4; ++sf) \
    P[sf] = *(const bf16x8*)(xq + (size_t)((cc)*4 + (sf>>1)*2)*PLANE_E + (r)*528 + ((sf&1)*32 + kxv)*8); }

#define MM(kkv, lo, hi) { \
  __builtin_amdgcn_s_setprio(1); \
  _Pragma("unroll") for (int sub = 0; sub < 2; ++sub) \
  _Pragma("unroll") for (int cbg = 0; cbg < 2; ++cbg) { \
    bf16x8 afr = *(const bf16x8*)(&wab[((kkv)*4 + sub*2 + cbg)*512 + lane*8]); \
    _Pragma("unroll") for (int f = 0; f < 2; ++f) { \
      acc[0][cbg][f] = __builtin_amdgcn_mfma_f32_32x32x16_bf16(afr, lo[sub*2+f], acc[0][cbg][f], 0,0,0); \
      acc[1][cbg][f] = __builtin_amdgcn_mfma_f32_32x32x16_bf16(afr, hi[sub*2+f], acc[1][cbg][f], 0,0,0); \
    } } \
  __builtin_amdgcn_s_setprio(0); }

#define STAGE_W(cc, b) { const bf16* seg = wnb + (size_t)(cc)*73728; \
  _Pragma("unroll") for (int i = 0; i < 9; ++i) { const int fid = i*4 + wv; \
    async16(&wa[b][fid*512], seg + (size_t)(fid>>2)*8192 + (fid&3)*512); } }

__global__ __launch_bounds__(256, 2)
void conv_kernel(const bf16* __restrict__ xb, const bf16* __restrict__ wn,
                 const float* __restrict__ pi, const float* __restrict__ Bbank,
                 float* __restrict__ y) {
  __shared__ __align__(16) bf16 wa[2][WA_E];   // 73728 B
  __shared__ float bns[64];
  const int tid = threadIdx.x;
  const int wv = tid >> 6, lane = tid & 63;
  const int l = lane & 31, u = lane >> 5;
  // XCD-aware swizzle (bijective, 1024 % 8 == 0)
  const int flat = blockIdx.x;
  const int wid = ((flat & 7) << 7) + (flat >> 3);
  const int n   = wid >> 5;
  const int hwb = (wid >> 2) & 7;
  const int cot = wid & 3;
  const int h0 = hwb * 8;

  const bf16* wnb = wn + (size_t)n*589824 + cot*2048 + lane*8;
  // per-lane x base: plane (n*32+u), padded row (h0+wv*2), col-slot l
  const bf16* xq = xb + (((size_t)(n*32 + u)*66 + (h0 + wv*2))*66 + l)*8;

  bf16x8 S[4][4];
  { const int kxv = 0; LDB(S[0], 0, 0) LDB(S[1], 1, 0) }  // chunk-0 prologue half
  STAGE_W(0, 0);

  if (tid < 64) {
    int co = cot*64 + tid;
    bns[tid] = pi[n*4+0]*Bbank[co*4+0] + pi[n*4+1]*Bbank[co*4+1]
             + pi[n*4+2]*Bbank[co*4+2] + pi[n*4+3]*Bbank[co*4+3];
  }

  f32x16 acc[2][2][2];
#pragma unroll
  for (int o = 0; o < 2; ++o)
#pragma unroll
    for (int a = 0; a < 2; ++a)
#pragma unroll
      for (int b = 0; b < 2; ++b)
#pragma unroll
        for (int k = 0; k < 16; ++k) acc[o][a][b][k] = 0.f;

  for (int c = 0; c < 8; ++c) {
    __syncthreads();            // drains: wa[c&1] DMAs + prefetched S0,S1; readers of wa[(c+1)&1] done
    { const int kxv = 0; LDB(S[2], 2, c) LDB(S[3], 3, c) }
    if (c < 7) STAGE_W(c + 1, (c + 1) & 1);
    const bf16* wab = wa[c & 1];
    const int cp = (c < 7) ? c + 1 : 7;
    // 9 steps, kx-major; rows: MM(ky) uses S[ky],S[ky+1]
    MM(0, S[0], S[1])
    MM(3, S[1], S[2]) { const int kxv = 1; LDB(S[0], 0, c) LDB(S[1], 1, c) }
    MM(6, S[2], S[3]) { const int kxv = 1; LDB(S[2], 2, c) }
    MM(1, S[0], S[1]) { const int kxv = 1; LDB(S[3], 3, c) }
    MM(4, S[1], S[2]) { const int kxv = 2; LDB(S[0], 0, c) LDB(S[1], 1, c) }
    MM(7, S[2], S[3]) { const int kxv = 2; LDB(S[2], 2, c) }
    MM(2, S[0], S[1]) { const int kxv = 2; LDB(S[3], 3, c) }
    MM(5, S[1], S[2]) { const int kxv = 0; LDB(S[0], 0, cp) LDB(S[1], 1, cp) }  // next-chunk prefetch
    MM(8, S[2], S[3])
  }
  // epilogue: 32x32 D: co-local = (reg&3)+8*(reg>>2)+4*u, w = f*32+l
#pragma unroll
  for (int o = 0; o < 2; ++o) {
    const int h = h0 + wv*2 + o;
#pragma unroll
    for (int cbg = 0; cbg < 2; ++cbg) {
#pragma unroll
      for (int f = 0; f < 2; ++f) {
        const int wcol = f*32 + l;
#pragma unroll
        for (int reg = 0; reg < 16; ++reg) {
          const int col = cbg*32 + (reg & 3) + 8*(reg >> 2) + 4*u;
          y[(((size_t)n*CO + cot*64 + col)*HH + h)*WW + wcol] = acc[o][cbg][f][reg] + bns[col];
        }
      }
    }
  }
}

extern "C" void kernel_launch(void* const* d_in, const int* in_sizes, int n_in,
                              void* d_out, int out_size, void* d_ws, size_t ws_size,
                              hipStream_t stream) {
  const float* x     = (const float*)d_in[0];
  const float* Wbank = (const float*)d_in[1];
  const float* Bbank = (const float*)d_in[2];
  const float* w1    = (const float*)d_in[3];
  const float* b1    = (const float*)d_in[4];
  const float* w2    = (const float*)d_in[5];
  const float* b2    = (const float*)d_in[6];
  float* y = (float*)d_out;

  bf16*  wn     = (bf16*)d_ws;                                  // 37.75 MB
  bf16*  xb     = (bf16*)((char*)d_ws + WN_BYTES);              // 71.37 MB (padded)
  float* pooled = (float*)((char*)d_ws + WN_BYTES + XB_BYTES);  // 32 KB
  float* pi     = pooled + NB*CI;                               // 512 B

  dim3 cg(32, NB);
  cvt_pool_kernel<<<cg, 256, 0, stream>>>(x, xb, pooled);
  attn_kernel<<<NB, HID, 0, stream>>>(pooled, w1, b1, w2, b2, pi);
  agg_kernel<<<288, 256, 0, stream>>>(Wbank, pi, wn);
  conv_kernel<<<1024, 256, 0, stream>>>(xb, wn, pi, Bbank, y);
}

// Round 12
// 193.530 us; speedup vs baseline: 1.0753x; 1.0753x over previous
//
#include <hip/hip_runtime.h>
#include <hip/hip_bf16.h>
#include <stdint.h>

typedef __bf16 bf16;
typedef __bf16 bf16x8 __attribute__((ext_vector_type(8)));
typedef float f32x4 __attribute__((ext_vector_type(4)));

#define TAU (1.0f/30.0f)

#define NB 32
#define CI 256
#define CO 256
#define HH 64
#define WW 64
#define HID 64

// wn fragment-linear layout: [n][c(8 ci-chunks)][kk(9)][cbg(16)][lane(64)][j(8)]
#define WN_ELEMS ((size_t)NB*8*9*16*512)
#define WN_BYTES (WN_ELEMS*2)
// xb padded layout: [n][cg(32)][hr(66)][wl(66)][j(8)] bf16, margins (hr/wl = 0 or 65) zeroed
#define PLANE_E 34848          // 66*66*8
#define XB_ELEMS ((size_t)NB*32*PLANE_E)
#define XB_BYTES (XB_ELEMS*2)  // 71.37 MB

__device__ __forceinline__ void async16(void* lds_uniform_base, const void* g_perlane) {
  __builtin_amdgcn_global_load_lds(
      (const __attribute__((address_space(1))) uint32_t*)g_perlane,
      (__attribute__((address_space(3))) uint32_t*)lds_uniform_base, 16, 0, 0);
}

// Fused fp32->bf16 repack (padded layout) + global average pool.
__global__ void cvt_pool_kernel(const float* __restrict__ x, bf16* __restrict__ xb,
                                float* __restrict__ pooled) {
  const int cg = blockIdx.x, n = blockIdx.y, tid = threadIdx.x;
  const float* base = x + ((size_t)n*CI + cg*8)*4096;
  bf16* ob = xb + ((size_t)n*32 + cg)*PLANE_E;
  // zero the 260 margin slots (hr=0, hr=65, wl=0, wl=65)
  for (int i = tid; i < 260; i += 256) {
    int hr, wl;
    if (i < 66)       { hr = 0;       wl = i; }
    else if (i < 132) { hr = 65;      wl = i - 66; }
    else if (i < 196) { hr = i - 131; wl = 0; }
    else              { hr = i - 195; wl = 65; }
    *(int4*)(ob + ((size_t)hr*66 + wl)*8) = int4{0,0,0,0};
  }
  float s[8];
#pragma unroll
  for (int j = 0; j < 8; ++j) s[j] = 0.f;
  for (int it = 0; it < 16; ++it) {
    int pos = it*256 + tid;
    int h = pos >> 6, w = pos & 63;
    bf16x8 o;
#pragma unroll
    for (int j = 0; j < 8; ++j) {
      float v = base[(size_t)j*4096 + pos];
      s[j] += v;
      o[j] = (bf16)v;
    }
    *(bf16x8*)(ob + ((size_t)(h+1)*66 + (w+1))*8) = o;
  }
  __shared__ float red[4][8];
#pragma unroll
  for (int j = 0; j < 8; ++j)
#pragma unroll
    for (int off = 32; off; off >>= 1) s[j] += __shfl_xor(s[j], off);
  int wv = tid >> 6, lane = tid & 63;
  if (lane == 0)
#pragma unroll
    for (int j = 0; j < 8; ++j) red[wv][j] = s[j];
  __syncthreads();
  if (tid < 8) {
    float t = red[0][tid] + red[1][tid] + red[2][tid] + red[3][tid];
    pooled[n*CI + cg*8 + tid] = t * (1.0f/4096.0f);
  }
}

__global__ void attn_kernel(const float* __restrict__ pooled,
                            const float* __restrict__ w1, const float* __restrict__ b1,
                            const float* __restrict__ w2, const float* __restrict__ b2,
                            float* __restrict__ pi) {
  int n = blockIdx.x, h = threadIdx.x;        // 64 threads
  __shared__ float hm[HID];
  __shared__ float lgs[4];
  const float* pr = pooled + n*CI;
  float s = b1[h];
  for (int c = 0; c < CI; ++c) s += pr[c] * w1[h*CI + c];
  hm[h] = s > 0.f ? s : 0.f;
  __syncthreads();
  if (h < 4) {
    float lg = b2[h];
    for (int k = 0; k < HID; ++k) lg += hm[k] * w2[h*HID + k];
    lgs[h] = lg * TAU;
  }
  __syncthreads();
  if (h == 0) {
    float mx = fmaxf(fmaxf(lgs[0], lgs[1]), fmaxf(lgs[2], lgs[3]));
    float e0 = expf(lgs[0]-mx), e1 = expf(lgs[1]-mx), e2 = expf(lgs[2]-mx), e3 = expf(lgs[3]-mx);
    float inv = 1.f / (e0+e1+e2+e3);
    pi[n*4+0] = e0*inv; pi[n*4+1] = e1*inv; pi[n*4+2] = e2*inv; pi[n*4+3] = e3*inv;
  }
}

__global__ void agg_kernel(const float* __restrict__ Wbank, const float* __restrict__ pi,
                           bf16* __restrict__ wn) {
  int wid = blockIdx.x * 4 + (threadIdx.x >> 6);   // 0..1151
  int lane = threadIdx.x & 63;
  int c = wid / 144;
  int rem = wid - c*144;
  int kk = rem >> 4;
  int cbg = rem & 15;
  int co  = cbg*16 + (lane & 15);
  int ci0 = c*32 + (lane >> 4)*8;
  float w[4][8];
#pragma unroll
  for (int m = 0; m < 4; ++m)
#pragma unroll
    for (int j = 0; j < 8; ++j)
      w[m][j] = Wbank[(size_t)((co*4 + m)*256 + ci0 + j)*9 + kk];
  for (int n = 0; n < NB; ++n) {
    float p0 = pi[n*4+0], p1 = pi[n*4+1], p2 = pi[n*4+2], p3 = pi[n*4+3];
    bf16x8 o;
#pragma unroll
    for (int j = 0; j < 8; ++j)
      o[j] = (bf16)(p0*w[0][j] + p1*w[1][j] + p2*w[2][j] + p3*w[3][j]);
    *(bf16x8*)(wn + ((size_t)n*1152 + c*144 + kk*16 + cbg)*512 + lane*8) = o;
  }
}

// Conv R12: R8 structure (8 rows x 64 co, 4 waves, wave owns 2 rows; A dbuf in LDS,
// B global->VGPR distance-2) but chunk barriers are RAW s_barrier (no vmcnt(0) drain).
// Correctness: vmcnt retires in order; STAGE_W(c) DMAs are issued before all chunk
// c-1 B-loads, and MM(8) waits on the s6 B-load, so each wave's DMAs are retired
// before it reaches the barrier. Prefetches stay in flight across barriers (T4).
#define WA_E (9*4*512)        // 18432 el = 36864 B per buffer

#define LDG(st, rr, kxx, cc) { _Pragma("unroll") \
  for (int f = 0; f < 4; ++f) \
    S[st][f] = *(const bf16x8*)(xu + ((size_t)(cc)*139392 + (rr)*528 + f*128 + (kxx)*8)); }

#define MM(kkv, lo, hi) { \
  __builtin_amdgcn_s_setprio(1); \
  _Pragma("unroll") for (int cb = 0; cb < 4; ++cb) { \
    bf16x8 afr = *(const bf16x8*)(&wab[(kkv)*2048 + cb*512 + lane*8]); \
    _Pragma("unroll") for (int f = 0; f < 4; ++f) { \
      acc[0][cb][f] = __builtin_amdgcn_mfma_f32_16x16x32_bf16(afr, lo[f], acc[0][cb][f], 0,0,0); \
      acc[1][cb][f] = __builtin_amdgcn_mfma_f32_16x16x32_bf16(afr, hi[f], acc[1][cb][f], 0,0,0); \
    } } \
  __builtin_amdgcn_s_setprio(0); }

#define STAGE_W(cc, b) { const bf16* seg = wnb + (size_t)(cc)*73728; \
  _Pragma("unroll") for (int kk = 0; kk < 9; ++kk) \
    async16(&wa[b][kk*2048 + wv*512], seg + (size_t)kk*8192); }

#define RAW_BAR() { __builtin_amdgcn_sched_barrier(0); \
                    __builtin_amdgcn_s_barrier(); \
                    __builtin_amdgcn_sched_barrier(0); }

__global__ __launch_bounds__(256, 2)
void conv_kernel(const bf16* __restrict__ xb, const bf16* __restrict__ wn,
                 const float* __restrict__ pi, const float* __restrict__ Bbank,
                 float* __restrict__ y) {
  __shared__ __align__(16) bf16 wa[2][WA_E];   // 73728 B
  __shared__ float bns[64];
  const int tid = threadIdx.x;
  const int wv = tid >> 6, lane = tid & 63;
  const int l = lane & 15, u = lane >> 4;
  // XCD-aware swizzle (bijective, 1024 % 8 == 0): each XCD owns 4 consecutive n's.
  const int flat = blockIdx.x;
  const int wid = ((flat & 7) << 7) + (flat >> 3);
  const int n   = wid >> 5;
  const int hwb = (wid >> 2) & 7;
  const int cot = wid & 3;
  const int h0 = hwb * 8;

  const bf16* wnb = wn + (size_t)n*1152*512 + (size_t)(cot*4 + wv)*512 + lane*8;
  // per-lane x base: plane (n*32+u), padded row (h0+wv*2), col-slot l
  const bf16* xu = xb + (((size_t)(n*32 + u)*66 + (h0 + wv*2))*66 + l)*8;

  bf16x8 S[4][4];
  STAGE_W(0, 0);                // 9 DMAs for chunk 0
  LDG(0, 0, 0, 0) LDG(1, 1, 0, 0)   // chunk-0 S0,S1 prologue

  if (tid < 64) {
    int co = cot*64 + tid;
    bns[tid] = pi[n*4+0]*Bbank[co*4+0] + pi[n*4+1]*Bbank[co*4+1]
             + pi[n*4+2]*Bbank[co*4+2] + pi[n*4+3]*Bbank[co*4+3];
  }

  f32x4 acc[2][4][4];
#pragma unroll
  for (int o = 0; o < 2; ++o)
#pragma unroll
    for (int a = 0; a < 4; ++a)
#pragma unroll
      for (int b = 0; b < 4; ++b)
#pragma unroll
        for (int k = 0; k < 4; ++k) acc[o][a][b][k] = 0.f;

  __syncthreads();              // ONE full drain: wa[0] + S0,S1 landed, bns visible

  for (int c = 0; c < 8; ++c) {
    if (c) RAW_BAR();           // raw barrier: prefetches stay in flight (counted waits)
    LDG(2, 2, 0, c) LDG(3, 3, 0, c)
    if (c < 7) STAGE_W(c + 1, (c + 1) & 1);   // chunk c-1 readers of this buffer done
    const bf16* wab = wa[c & 1];
    const int cp = (c < 7) ? c + 1 : 7;
    // 9 MM steps; B loads distance-2 from use; s7 prefetches next chunk's S0,S1
    MM(0, S[0], S[1])
    MM(3, S[1], S[2]) LDG(0, 0, 1, c) LDG(1, 1, 1, c)
    MM(6, S[2], S[3]) LDG(2, 2, 1, c)
    MM(1, S[0], S[1]) LDG(3, 3, 1, c)
    MM(4, S[1], S[2]) LDG(0, 0, 2, c) LDG(1, 1, 2, c)
    MM(7, S[2], S[3]) LDG(2, 2, 2, c)
    MM(2, S[0], S[1]) LDG(3, 3, 2, c)
    MM(5, S[1], S[2]) LDG(0, 0, 0, cp) LDG(1, 1, 0, cp)
    MM(8, S[2], S[3])
  }
  // epilogue: D row=(lane>>4)*4+reg -> co, col=lane&15 -> w
#pragma unroll
  for (int o = 0; o < 2; ++o) {
    const int h = h0 + wv*2 + o;
#pragma unroll
    for (int cb = 0; cb < 4; ++cb) {
#pragma unroll
      for (int f = 0; f < 4; ++f) {
        const int wcol = f*16 + l;
#pragma unroll
        for (int r4 = 0; r4 < 4; ++r4) {
          const int col = cb*16 + u*4 + r4;
          y[(((size_t)n*CO + cot*64 + col)*HH + h)*WW + wcol] = acc[o][cb][f][r4] + bns[col];
        }
      }
    }
  }
}

extern "C" void kernel_launch(void* const* d_in, const int* in_sizes, int n_in,
                              void* d_out, int out_size, void* d_ws, size_t ws_size,
                              hipStream_t stream) {
  const float* x     = (const float*)d_in[0];
  const float* Wbank = (const float*)d_in[1];
  const float* Bbank = (const float*)d_in[2];
  const float* w1    = (const float*)d_in[3];
  const float* b1    = (const float*)d_in[4];
  const float* w2    = (const float*)d_in[5];
  const float* b2    = (const float*)d_in[6];
  float* y = (float*)d_out;

  bf16*  wn     = (bf16*)d_ws;                                  // 37.75 MB
  bf16*  xb     = (bf16*)((char*)d_ws + WN_BYTES);              // 71.37 MB (padded)
  float* pooled = (float*)((char*)d_ws + WN_BYTES + XB_BYTES);  // 32 KB
  float* pi     = pooled + NB*CI;                               // 512 B

  dim3 cg(32, NB);
  cvt_pool_kernel<<<cg, 256, 0, stream>>>(x, xb, pooled);
  attn_kernel<<<NB, HID, 0, stream>>>(pooled, w1, b1, w2, b2, pi);
  agg_kernel<<<288, 256, 0, stream>>>(Wbank, pi, wn);
  conv_kernel<<<1024, 256, 0, stream>>>(xb, wn, pi, Bbank, y);
}